// Round 2
// baseline (238.370 us; speedup 1.0000x reference)
//
#include <hip/hip_runtime.h>

// DCT 8x8 per block: out_block = D * X^T * D^T (verified round 1, absmax 0.016).
//
// Round-2 restructure: the R1 kernel (thread-per-block, 32B lane stride) ran at
// 2.2 TB/s because every vmem instruction used only half of each 128B line.
// Now: WG=256 handles one contiguous 512x16 strip (8192 floats = 128 blocks).
//   1) cooperative DENSE global->reg->LDS load (lane-contiguous float4),
//   2) LDS corner-turn into block-major layout (stride 68 floats: 16B-aligned,
//      bank-start 4l%32 tiles all banks -> conflict-free b128),
//   3) 2 threads per block, each computes 4 output rows (512 FMA),
//   4) results back to LDS, cooperative dense store.
// LDS 34816B -> 4 WG/CU = 16 waves/CU.

#define IMG 512
#define TILE_ROWS 16
#define TILE_FLOATS (IMG * TILE_ROWS)   // 8192
#define NBLK 128                        // 8x8 blocks per tile (64 wide x 2 tall)
#define BSTRIDE 68                      // padded floats per block (272B, 16B aligned)

__global__ __launch_bounds__(256, 4) void dct8x8_tile(
    const float* __restrict__ x,
    const float* __restrict__ dct,
    float* __restrict__ out)
{
    __shared__ float lds[NBLK * BSTRIDE];   // 34816 B
    __shared__ float D[64];

    const int t = threadIdx.x;
    if (t < 64) D[t] = dct[t];

    const size_t tileBase = (size_t)blockIdx.x * TILE_FLOATS;
    const float4* __restrict__ src = (const float4*)(x + tileBase);
    float4*       __restrict__ dst = (float4*)(out + tileBase);

    // ---- 1) dense cooperative load: 8 x (1KB per wave) ----
    float4 v[8];
    #pragma unroll
    for (int k = 0; k < 8; ++k) v[k] = src[k * 256 + t];

    // ---- corner-turn into block-major LDS ----
    #pragma unroll
    for (int k = 0; k < 8; ++k) {
        int o   = (k * 256 + t) * 4;        // float offset within tile
        int row = o >> 9;                   // /512  (0..15)
        int col = o & 511;
        int blk = ((row >> 3) << 6) + (col >> 3);
        int addr = blk * BSTRIDE + ((row & 7) << 3) + (col & 7);
        *(float4*)(lds + addr) = v[k];
    }
    __syncthreads();

    // ---- 2) per-thread compute: 2 threads per block, 4 output rows each ----
    const int blk = t & (NBLK - 1);
    const int uh  = (t >> 7) << 2;          // 0 or 4
    float* bp = lds + blk * BSTRIDE;

    float xr[8][8];
    #pragma unroll
    for (int r = 0; r < 8; ++r) {
        float4 a = *(const float4*)(bp + r * 8);
        float4 b = *(const float4*)(bp + r * 8 + 4);
        xr[r][0] = a.x; xr[r][1] = a.y; xr[r][2] = a.z; xr[r][3] = a.w;
        xr[r][4] = b.x; xr[r][5] = b.y; xr[r][6] = b.z; xr[r][7] = b.w;
    }

    float o4[4][8];
    #pragma unroll
    for (int u = 0; u < 4; ++u) {
        const int uu = uh + u;
        float z[8];
        #pragma unroll
        for (int j = 0; j < 8; ++j) {
            float s = 0.0f;
            #pragma unroll
            for (int i = 0; i < 8; ++i) s += D[uu * 8 + i] * xr[j][i];
            z[j] = s;
        }
        #pragma unroll
        for (int vv = 0; vv < 8; ++vv) {
            float s = 0.0f;
            #pragma unroll
            for (int j = 0; j < 8; ++j) s += z[j] * D[vv * 8 + j];
            o4[u][vv] = s;
        }
    }
    __syncthreads();   // all reads of lds done before anyone overwrites

    #pragma unroll
    for (int u = 0; u < 4; ++u) {
        *(float4*)(bp + (uh + u) * 8)     = make_float4(o4[u][0], o4[u][1], o4[u][2], o4[u][3]);
        *(float4*)(bp + (uh + u) * 8 + 4) = make_float4(o4[u][4], o4[u][5], o4[u][6], o4[u][7]);
    }
    __syncthreads();

    // ---- 4) dense cooperative store ----
    #pragma unroll
    for (int k = 0; k < 8; ++k) {
        int o   = (k * 256 + t) * 4;
        int row = o >> 9;
        int col = o & 511;
        int blk2 = ((row >> 3) << 6) + (col >> 3);
        int addr = blk2 * BSTRIDE + ((row & 7) << 3) + (col & 7);
        dst[k * 256 + t] = *(const float4*)(lds + addr);
    }
}

extern "C" void kernel_launch(void* const* d_in, const int* in_sizes, int n_in,
                              void* d_out, int out_size, void* d_ws, size_t ws_size,
                              hipStream_t stream) {
    const float* x   = (const float*)d_in[0];
    const float* dct = (const float*)d_in[1];
    float* out = (float*)d_out;

    const int total_floats = 32 * 3 * 512 * 512;       // 25165824
    const int grid = total_floats / TILE_FLOATS;       // 3072
    dct8x8_tile<<<grid, 256, 0, stream>>>(x, dct, out);
}

// Round 3
// 176.670 us; speedup vs baseline: 1.3492x; 1.3492x over previous
//
#include <hip/hip_runtime.h>

// out_block = D * X^T * D^T = (D*X*D^T)^T  (verified R1, absmax 0.016).
// Separable: passA = vertical 8-pt DCT per column; passB = horizontal 8-pt DCT
// per row-segment; then transpose within each 8x8 block; all staged in LDS.
// DCT-8 uses even/odd symmetry with hardcoded f32 basis constants
// (bit-identical to float32(cos(...)) basis the reference uses).
//
// R2 post-mortem: whole-block-per-thread compute spilled to scratch
// (WRITE_SIZE 252 MB vs 96 MB output). This version keeps <= ~40 live VGPRs.

#define RS 516                  // LDS row stride in floats (16B-aligned, padded)
#define TILE_FLOATS 4096        // 8 rows x 512 cols strip per workgroup

__device__ __forceinline__ void dct8(float x0, float x1, float x2, float x3,
                                     float x4, float x5, float x6, float x7,
                                     float z[8]) {
    // even/odd decomposition: D[u][7-x] = (-1)^u D[u][x]
    float s0 = x0 + x7, s1 = x1 + x6, s2 = x2 + x5, s3 = x3 + x4;
    float d0 = x0 - x7, d1 = x1 - x6, d2 = x2 - x5, d3 = x3 - x4;
    const float A = 0.3535533906f;  // 1/sqrt(8), 0.5*cos(4pi/16)
    const float B = 0.4903926402f;  // 0.5*cos(1pi/16)
    const float C = 0.4619397663f;  // 0.5*cos(2pi/16)
    const float E = 0.4157348061f;  // 0.5*cos(3pi/16)
    const float F = 0.2777851165f;  // 0.5*cos(5pi/16)
    const float G = 0.1913417162f;  // 0.5*cos(6pi/16)
    const float H = 0.0975451610f;  // 0.5*cos(7pi/16)
    z[0] = A * (s0 + s1 + s2 + s3);
    z[2] = C * s0 + G * s1 - G * s2 - C * s3;
    z[4] = A * (s0 - s1 - s2 + s3);
    z[6] = G * s0 - C * s1 + C * s2 - G * s3;
    z[1] = B * d0 + E * d1 + F * d2 + H * d3;
    z[3] = E * d0 - H * d1 - B * d2 - F * d3;
    z[5] = F * d0 - B * d1 + H * d2 + E * d3;
    z[7] = H * d0 - F * d1 + E * d2 - B * d3;
}

__global__ __launch_bounds__(256) void dct8x8_sep(
    const float* __restrict__ x, float* __restrict__ out)
{
    __shared__ float s[8 * RS];   // 16512 B

    const int t = threadIdx.x;
    const size_t base = (size_t)blockIdx.x * TILE_FLOATS;
    const float4* __restrict__ src = (const float4*)(x + base);
    float4*       __restrict__ dst = (float4*)(out + base);

    // ---- stage 1: dense global load -> LDS image layout ----
    #pragma unroll
    for (int k = 0; k < 4; ++k) {
        int o = (k * 256 + t) * 4;
        int row = o >> 9, col = o & 511;
        float4 v = src[k * 256 + t];
        *(float4*)(s + row * RS + col) = v;   // contiguous per wave: conflict-free
    }
    __syncthreads();

    // ---- pass A: vertical DCT down each column (in place, thread-private) ----
    #pragma unroll
    for (int k = 0; k < 2; ++k) {
        int c = k * 256 + t;
        float z[8];
        dct8(s[0*RS+c], s[1*RS+c], s[2*RS+c], s[3*RS+c],
             s[4*RS+c], s[5*RS+c], s[6*RS+c], s[7*RS+c], z);
        #pragma unroll
        for (int u = 0; u < 8; ++u) s[u * RS + c] = z[u];
    }
    __syncthreads();

    // ---- pass B: horizontal DCT per (row r, block b); hold results in regs ----
    float res[2][8];
    #pragma unroll
    for (int k = 0; k < 2; ++k) {
        int id = k * 256 + t;
        int r = id & 7, b = id >> 3;
        const float* p = s + r * RS + b * 8;
        float4 a = *(const float4*)p;
        float4 q = *(const float4*)(p + 4);
        dct8(a.x, a.y, a.z, a.w, q.x, q.y, q.z, q.w, res[k]);
    }
    __syncthreads();   // all pass-B reads done before transposed writes

    // ---- transpose within block: res[k][v] -> (row v, col 8b + r) ----
    #pragma unroll
    for (int k = 0; k < 2; ++k) {
        int id = k * 256 + t;
        int r = id & 7, b = id >> 3;
        #pragma unroll
        for (int v = 0; v < 8; ++v)
            s[v * RS + b * 8 + r] = res[k][v];   // 2-way bank alias: free
    }
    __syncthreads();

    // ---- stage 3: dense LDS -> global store ----
    #pragma unroll
    for (int k = 0; k < 4; ++k) {
        int o = (k * 256 + t) * 4;
        int row = o >> 9, col = o & 511;
        dst[k * 256 + t] = *(const float4*)(s + row * RS + col);
    }
}

extern "C" void kernel_launch(void* const* d_in, const int* in_sizes, int n_in,
                              void* d_out, int out_size, void* d_ws, size_t ws_size,
                              hipStream_t stream) {
    const float* x = (const float*)d_in[0];
    float* out = (float*)d_out;
    const int total_floats = 32 * 3 * 512 * 512;       // 25165824
    const int grid = total_floats / TILE_FLOATS;       // 6144
    dct8x8_sep<<<grid, 256, 0, stream>>>(x, out);
}

// Round 4
// 172.759 us; speedup vs baseline: 1.3798x; 1.0226x over previous
//
#include <hip/hip_runtime.h>

// out_block = (D*X*D^T)^T, separable (verified R1/R3, absmax 0.0156).
//
// R4: barrier-free wave-autonomous design. R3's 4 __syncthreads on a 16KB
// tile were the bottleneck (on-CU issue ~17us, HBM floor ~30us, measured 60us).
// Each WAVE owns one 8x64 strip (8 blocks):
//   producer lane (b,c): 8 dense dword loads (64 consecutive floats/instr),
//     vertical DCT-8 in regs, two dense b128 writes of z^T to a per-wave slab;
//   consumer lane (v,b): 16 b128 reads (lane-dense + 8-way broadcast, 1 bank
//     phase each), 64 FMA vs D row v (global, wave-broadcast, L1), 2 float4
//     stores of output row v.
// No __syncthreads anywhere; intra-wave RAW handled by compiler lgkmcnt.

#define IMGW 512

__device__ __forceinline__ void dct8v(const float x[8], float z[8]) {
    float s0 = x[0] + x[7], s1 = x[1] + x[6], s2 = x[2] + x[5], s3 = x[3] + x[4];
    float d0 = x[0] - x[7], d1 = x[1] - x[6], d2 = x[2] - x[5], d3 = x[3] - x[4];
    const float A = 0.3535533906f;  // 1/sqrt(8)
    const float B = 0.4903926402f;  // 0.5*cos(1pi/16)
    const float C = 0.4619397663f;  // 0.5*cos(2pi/16)
    const float E = 0.4157348061f;  // 0.5*cos(3pi/16)
    const float F = 0.2777851165f;  // 0.5*cos(5pi/16)
    const float G = 0.1913417162f;  // 0.5*cos(6pi/16)
    const float H = 0.0975451610f;  // 0.5*cos(7pi/16)
    z[0] = A * (s0 + s1 + s2 + s3);
    z[2] = C * s0 + G * s1 - G * s2 - C * s3;
    z[4] = A * (s0 - s1 - s2 + s3);
    z[6] = G * s0 - C * s1 + C * s2 - G * s3;
    z[1] = B * d0 + E * d1 + F * d2 + H * d3;
    z[3] = E * d0 - H * d1 - B * d2 - F * d3;
    z[5] = F * d0 - B * d1 + H * d2 + E * d3;
    z[7] = H * d0 - F * d1 + E * d2 - B * d3;
}

__global__ __launch_bounds__(256) void dct8x8_wave(
    const float* __restrict__ x,
    const float* __restrict__ dct,
    float* __restrict__ out)
{
    __shared__ float vt[4 * 512];            // 2 KB per wave, 8 KB per WG

    const int t    = threadIdx.x;
    const int lane = t & 63;
    const int wl   = t >> 6;
    const int strip = blockIdx.x * 4 + wl;   // 0 .. 49151

    // strip = 8 rows x 64 cols; 8 strips per 8-row band, 6144 bands.
    const size_t base = (size_t)(strip >> 3) * (8 * IMGW) + (size_t)(strip & 7) * 64;

    // ---- producer: lane = b*8 + c owns column (b*8+c) of the strip ----
    const float* src = x + base + lane;
    float col[8];
    #pragma unroll
    for (int r = 0; r < 8; ++r) col[r] = src[r * IMGW];   // dense 256B/instr

    float z[8];
    dct8v(col, z);

    float* wb = vt + wl * 512;
    const int wi = ((lane & 7) * 8 + (lane >> 3)) * 4;    // chunk (c*8+b)
    *(float4*)(wb + wi)       = make_float4(z[0], z[1], z[2], z[3]);
    *(float4*)(wb + 256 + wi) = make_float4(z[4], z[5], z[6], z[7]);

    // ---- consumer: lane = v*8 + b2 produces output row v of block b2 ----
    const int v  = lane >> 3;
    const int b2 = lane & 7;

    const float4 dA = ((const float4*)dct)[v * 2];        // D[v][0..3]
    const float4 dB = ((const float4*)dct)[v * 2 + 1];    // D[v][4..7]
    const float dr[8] = { dA.x, dA.y, dA.z, dA.w, dB.x, dB.y, dB.z, dB.w };

    float acc[8];
    #pragma unroll
    for (int u = 0; u < 8; ++u) acc[u] = 0.0f;

    #pragma unroll
    for (int c = 0; c < 8; ++c) {
        const int ri = (c * 8 + b2) * 4;                  // dense+broadcast read
        const float4 a = *(const float4*)(wb + ri);       // V[0..3][c]
        const float4 q = *(const float4*)(wb + 256 + ri); // V[4..7][c]
        const float dc = dr[c];
        acc[0] += dc * a.x;  acc[1] += dc * a.y;
        acc[2] += dc * a.z;  acc[3] += dc * a.w;
        acc[4] += dc * q.x;  acc[5] += dc * q.y;
        acc[6] += dc * q.z;  acc[7] += dc * q.w;
    }

    // out[v][u] = sum_c D[v][c] * V[u][c]  -> row v of block b2
    float* dp = out + base + (size_t)v * IMGW + b2 * 8;
    *(float4*)dp       = make_float4(acc[0], acc[1], acc[2], acc[3]);
    *(float4*)(dp + 4) = make_float4(acc[4], acc[5], acc[6], acc[7]);
}

extern "C" void kernel_launch(void* const* d_in, const int* in_sizes, int n_in,
                              void* d_out, int out_size, void* d_ws, size_t ws_size,
                              hipStream_t stream) {
    const float* x   = (const float*)d_in[0];
    const float* dct = (const float*)d_in[1];
    float* out = (float*)d_out;

    // 32*3*512*512 floats / (8*64 per strip) = 49152 strips; 4 waves per WG.
    const int grid = 49152 / 4;   // 12288
    dct8x8_wave<<<grid, 256, 0, stream>>>(x, dct, out);
}